// Round 6
// baseline (3016.329 us; speedup 1.0000x reference)
//
#include <hip/hip_runtime.h>
#include <hip/hip_bf16.h>

// ============================================================================
// GRU seq2seq (3-layer enc + 3-cell dec + linear), B=2048, H=60, F=1, fp32.
//
// Round 6: decoupled wave-group pipeline (replaces block-wide lockstep).
//  - 128 blocks x 16 rows, 12 waves (4 per group). Each group self-times via
//    per-wave LDS progress counters (single writer each) + s_sleep spin;
//    4-deep LDS ring lets groups drift ~2 steps -> VALU/MFMA/LDS phases of
//    different groups overlap (round 5 showed lockstep serializes the pipes).
//  - Wait rules (prog[g][w] = completed steps of wave w of group g):
//      own:      min(prog[g])   >= t      (h_{t-1} complete)
//      producer: min(prog[g-1]) >= t+1    (x = h^{g-1}_t ready)      [g>0]
//      anti:     min(prog[g+1]) >= t-3    (ring slot t-4 consumed)   [g<2]
//      g2-dec:   prog[0][0]     >= t+2    (y-reader done with h2_{t-4})
//      y (g0w0, dec): min(prog[2]) >= t-4, y_t-5 = h2_{t-5} @ Lw (MFMA)
//  - Bias-as-column-60: ring col 60 == 1.0 (hi) permanently; bhh folded into
//    Whh frags col 60 (hi+lo via mm3), bih into Wx frags col 60 (hi; lo kept
//    as scalar acc-init residual), lin_b into Lw col 60. No per-step bias VALU.
//  - Free LDS XOR swizzle: 8-short col-blocks XORed with row>>2 (per-lane
//    const in both write and read addressing) -> b16 write bursts hit all 32
//    banks (was 4-way aliased).
//  - Kept from best (r2): hi/lo bf16 ring planes, mm3 h-path / mm2 x-path,
//    VGPR/AGPR-resident weights, x prefetch, lgkmcnt-only fencing.
// ============================================================================

typedef float  f32x4  __attribute__((ext_vector_type(4)));
typedef short  bf16x8 __attribute__((ext_vector_type(8)));

struct CellB  { const float* bih; const float* wih_vec; };
struct PhaseArgs {
  const float* xseq;          // [2048][512] fp32
  const unsigned short* frags;
  CellB cell[3];
  const float* hfin_rd;       // dec: [3][2048][64] fp32
  float* hfin_wr;             // enc
  const float* lin_b;         // [1]
  float* y;                   // [2048][512]
};
struct PrepArgs {
  const float* w[13];         // (wih,whh) x 6 cells, then lin_w
  const float* b[13];         // (bih,bhh) x 6 cells, then lin_b
  int din[13];
  unsigned short* out;
};

__device__ __forceinline__ unsigned int rne16(float x) {
  unsigned int u = __float_as_uint(x);
  return (u + 0x7fffu + ((u >> 16) & 1u)) >> 16;
}
__device__ __forceinline__ float bf2f(unsigned int b) { return __uint_as_float(b << 16); }
union BU { __hip_bfloat16 b; unsigned short u; };
__device__ __forceinline__ unsigned short f2bf(float x) { BU c; c.b = __float2bfloat16(x); return c.u; }
__device__ __forceinline__ float bfu2f(unsigned short s) { BU c; c.u = s; return __bfloat162float(c.b); }
__device__ __forceinline__ float bfres(float v) { return v - bfu2f(f2bf(v)); }

// ---------------------------------------------------------------------------
// Prep: B-fragments (bf16 hi/lo), K=64 incl. bias column k=60.
// frag_idx = (cm*12 + tile)*4 + s2*2 + sp; short off = frag_idx*512 + lane*8 + e
// cm = cell*2+mat (6 cells x {wih,whh}); cm=12 = lin_w (tile 0, col 0 only).
// element: col c = tile*16+(lane&15); k = s2*32+(lane>>4)*8+e.
// k==60 -> bias (bih for wih/din60, bhh for whh, lin_b for lin).
// ---------------------------------------------------------------------------
__global__ void prep_frags(PrepArgs P) {
  int id = blockIdx.x * 256 + threadIdx.x;       // 1160*256 = 296960
  int e    = id & 7;
  int lane = (id >> 3) & 63;
  int sp   = (id >> 9) & 1;
  int s2   = (id >> 10) & 1;
  int rest = id >> 11;
  int tile = rest % 12;
  int cm   = rest / 12;
  if (cm > 12) return;
  const float* W = P.w[cm];
  const float* B = P.b[cm];
  int din = P.din[cm];
  int c = tile * 16 + (lane & 15);
  int k = s2 * 32 + (lane >> 4) * 8 + e;
  float v = 0.f;
  if (cm == 12) {
    if (c == 0) { if (k < 60) v = W[k]; else if (k == 60) v = B[0]; }
  } else {
    int j = c & 63, sec = c >> 6;
    if (j < 60) {
      if (k < din) v = W[(sec * 60 + j) * din + k];
      else if (k == 60 && din == 60) v = B[sec * 60 + j];
    }
  }
  unsigned int hi = rne16(v);
  unsigned short o = (unsigned short)(sp ? rne16(v - bf2f(hi)) : hi);
  P.out[id] = o;
}

// 3-product (hi*Whi + lo*Whi + hi*Wlo), two independent 3-deep chains
__device__ __forceinline__ f32x4 mm3(f32x4 acc, const bf16x8 Ahi[2],
                                     const bf16x8 Alo[2], const bf16x8 B[2][2]) {
  f32x4 a2 = {0.f, 0.f, 0.f, 0.f};
  acc = __builtin_amdgcn_mfma_f32_16x16x32_bf16(Ahi[0], B[0][0], acc, 0, 0, 0);
  a2  = __builtin_amdgcn_mfma_f32_16x16x32_bf16(Alo[0], B[0][0], a2,  0, 0, 0);
  acc = __builtin_amdgcn_mfma_f32_16x16x32_bf16(Ahi[1], B[1][0], acc, 0, 0, 0);
  a2  = __builtin_amdgcn_mfma_f32_16x16x32_bf16(Alo[1], B[1][0], a2,  0, 0, 0);
  acc = __builtin_amdgcn_mfma_f32_16x16x32_bf16(Ahi[0], B[0][1], acc, 0, 0, 0);
  a2  = __builtin_amdgcn_mfma_f32_16x16x32_bf16(Ahi[1], B[1][1], a2,  0, 0, 0);
  return acc + a2;
}
// 2-product (hi*Whi + lo*Whi)
__device__ __forceinline__ f32x4 mm2(f32x4 acc, const bf16x8 Ahi[2],
                                     const bf16x8 Alo[2], const bf16x8 B[2]) {
  f32x4 a2 = {0.f, 0.f, 0.f, 0.f};
  acc = __builtin_amdgcn_mfma_f32_16x16x32_bf16(Ahi[0], B[0], acc, 0, 0, 0);
  a2  = __builtin_amdgcn_mfma_f32_16x16x32_bf16(Alo[0], B[0], a2,  0, 0, 0);
  acc = __builtin_amdgcn_mfma_f32_16x16x32_bf16(Ahi[1], B[1], acc, 0, 0, 0);
  a2  = __builtin_amdgcn_mfma_f32_16x16x32_bf16(Alo[1], B[1], a2,  0, 0, 0);
  return acc + a2;
}

// ---------------------------------------------------------------------------
// Progress-counter waits (uniform LDS reads, s_sleep backoff).
// ---------------------------------------------------------------------------
__device__ __forceinline__ unsigned min4v(const volatile unsigned* p) {
  unsigned a = p[0], b = p[1], c = p[2], d = p[3];
  unsigned ab = a < b ? a : b, cd = c < d ? c : d;
  return ab < cd ? ab : cd;
}
__device__ __forceinline__ void wait4(const volatile unsigned* p, int T) {
  if (T <= 0) return;
  while ((int)min4v(p) < T) __builtin_amdgcn_s_sleep(2);
  asm volatile("" ::: "memory");
  __builtin_amdgcn_sched_barrier(0);
}
__device__ __forceinline__ void wait1(const volatile unsigned* p, int T) {
  if (T <= 0) return;
  while ((int)p[0] < T) __builtin_amdgcn_s_sleep(2);
  asm volatile("" ::: "memory");
  __builtin_amdgcn_sched_barrier(0);
}

// ---------------------------------------------------------------------------
template <int IS_DEC>
__global__ __launch_bounds__(768, 3) void gru_phase(PhaseArgs P) {
  __shared__ alignas(16) unsigned short ringH[3 * 4 * 16 * 72];  // [g][slot][row][colPhys]
  __shared__ alignas(16) unsigned short ringL[3 * 4 * 16 * 72];
  __shared__ unsigned prog[12];                                  // [g*4+w]

  const int tid  = threadIdx.x;
  const int lane = tid & 63;
  const int wid  = tid >> 6;
  const int g    = wid >> 2;
  const int w    = wid & 3;
  const int c16  = lane & 15;
  const int q16  = lane >> 4;
  const int row_base = blockIdx.x * 16;
  const int c    = w * 16 + c16;
  const bool cv  = (c < 60);
  const int cell = (IS_DEC ? 3 : 0) + g;
  const bool din1 = (g == 0);
  const bool yduty = (IS_DEC && g == 0 && w == 0);

  // swizzled addressing (8-short blocks XORed with row>>2; per-lane constant)
  const int pcw = (c16 & 7) | ((((w * 2 + (c16 >> 3)) ^ q16) & 7) << 3); // write col
  const int rdo = c16 * 72 + 8 * (q16 ^ (c16 >> 2));                     // read base (+32 for s2=1)

  // bias residuals (hi part lives in weight-frag col 60)
  const float* bih = P.cell[g].bih;
  float b_r = 0.f, b_z = 0.f, b_in = 0.f;
  if (cv) {
    if (din1) { b_r = bih[c]; b_z = bih[60 + c]; b_in = bih[120 + c]; }
    else      { b_r = bfres(bih[c]); b_z = bfres(bih[60 + c]); b_in = bfres(bih[120 + c]); }
  }
  float w_r = 0.f, w_z = 0.f, w_n = 0.f;
  if (din1 && cv) {
    const float* wv = P.cell[g].wih_vec;
    w_r = wv[c]; w_z = wv[60 + c]; w_n = wv[120 + c];
  }
  float lbres = 0.f;
  if (yduty) lbres = bfres(P.lin_b[0]);

  // weight fragments (Bh: hi/lo; Bx, Lw: hi only)
  bf16x8 Bh[3][2][2], Bx[3][2], Lw[2];
#pragma unroll
  for (int T = 0; T < 3; ++T)
#pragma unroll
    for (int s2 = 0; s2 < 2; ++s2) {
      const int tile = w + 4 * T;
#pragma unroll
      for (int sp = 0; sp < 2; ++sp)
        Bh[T][s2][sp] = *(const bf16x8*)(P.frags +
            (size_t)(((cell * 2 + 1) * 12 + tile) * 4 + s2 * 2 + sp) * 512 + lane * 8);
    }
  if (!din1) {
#pragma unroll
    for (int T = 0; T < 3; ++T)
#pragma unroll
      for (int s2 = 0; s2 < 2; ++s2) {
        const int tile = w + 4 * T;
        Bx[T][s2] = *(const bf16x8*)(P.frags +
            (size_t)(((cell * 2 + 0) * 12 + tile) * 4 + s2 * 2 + 0) * 512 + lane * 8);
      }
  }
  if (yduty) {
#pragma unroll
    for (int s2 = 0; s2 < 2; ++s2)
      Lw[s2] = *(const bf16x8*)(P.frags +
          (size_t)((12 * 12 + 0) * 4 + s2 * 2 + 0) * 512 + lane * 8);
  }

  // ring init: col 60 = 1.0 (bias column) in all 4 slots; h0 into slot 3
  if (w == 3 && c16 >= 12) {
    const unsigned short hv = (c16 == 12) ? (unsigned short)0x3F80 : (unsigned short)0;
    const int pc60 = (c16 & 7) | (((7 ^ q16) & 7) << 3);
#pragma unroll
    for (int sl = 0; sl < 4; ++sl)
#pragma unroll
      for (int q = 0; q < 4; ++q) {
        const int idx = ((g * 4 + sl) * 16 + 4 * q16 + q) * 72 + pc60;
        ringH[idx] = hv; ringL[idx] = 0;
      }
  }
  float hreg[4];
#pragma unroll
  for (int q = 0; q < 4; ++q) {
    float h0 = 0.f;
    if (IS_DEC && cv)
      h0 = P.hfin_rd[((size_t)(2 - g) * 2048 + row_base + 4 * q16 + q) * 64 + c];
    hreg[q] = h0;
    if (cv) {
      const int idx = ((g * 4 + 3) * 16 + 4 * q16 + q) * 72 + pcw;
      unsigned short hb = f2bf(h0);
      ringH[idx] = hb;
      ringL[idx] = f2bf(h0 - bfu2f(hb));
    }
  }
  if (tid < 12) prog[tid] = 0;

  float xcur[4] = {0.f, 0.f, 0.f, 0.f};
  if (din1) {
    const float* xp = P.xseq + (size_t)row_base * 512;
#pragma unroll
    for (int q = 0; q < 4; ++q) xcur[q] = xp[(size_t)(4 * q16 + q) * 512];
  }
  __syncthreads();

  const volatile unsigned* vp = (const volatile unsigned*)prog;
  const int NT = yduty ? 517 : 512;
#pragma unroll 1
  for (int t = 0; t < NT; ++t) {
    if (t < 512) {
      // combined fast-path check (one read burst), then individual spins
      int ok = ((int)min4v(vp + 4 * g) >= t);
      if (!din1) ok &= ((int)min4v(vp + 4 * (g - 1)) >= t + 1);
      if (g < 2) ok &= ((int)min4v(vp + 4 * (g + 1)) >= t - 3);
      else if (IS_DEC) ok &= ((int)vp[0] >= t + 2);
      if (!ok) {
        wait4(vp + 4 * g, t);
        if (!din1) wait4(vp + 4 * (g - 1), t + 1);
        if (g < 2) wait4(vp + 4 * (g + 1), t - 3);
        else if (IS_DEC) wait1(vp, t + 2);
      }
      asm volatile("" ::: "memory");
      __builtin_amdgcn_sched_barrier(0);
    }

    // decoder y: y_{t-5} = h2_{t-5} @ lin + lin_b (MFMA on g0w0)
    if (yduty && t >= 5) {
      const int ty = t - 5;
      wait4(vp + 8, t - 4);
      const int yb = (8 + (ty & 3)) * 1152 + rdo;
      bf16x8 Yhi[2], Ylo[2];
      Yhi[0] = *(const bf16x8*)(ringH + yb);
      Yhi[1] = *(const bf16x8*)(ringH + yb + 32);
      Ylo[0] = *(const bf16x8*)(ringL + yb);
      Ylo[1] = *(const bf16x8*)(ringL + yb + 32);
      f32x4 ya = {lbres, lbres, lbres, lbres};
      ya = mm2(ya, Yhi, Ylo, Lw);
      if (c16 == 0) {
#pragma unroll
        for (int q = 0; q < 4; ++q)
          P.y[(size_t)(row_base + 4 * q16 + q) * 512 + ty] = ya[q];
      }
    }

    if (t < 512) {
      // ---- A loads (own h_{t-1} from slot (t+3)&3; x from g-1 slot t&3)
      const int ob = (g * 4 + ((t + 3) & 3)) * 1152 + rdo;
      bf16x8 Ahi[2], Alo[2];
      Ahi[0] = *(const bf16x8*)(ringH + ob);
      Ahi[1] = *(const bf16x8*)(ringH + ob + 32);
      Alo[0] = *(const bf16x8*)(ringL + ob);
      Alo[1] = *(const bf16x8*)(ringL + ob + 32);
      bf16x8 Xhi[2], Xlo[2];
      if (!din1) {
        const int xb = ((g - 1) * 4 + (t & 3)) * 1152 + rdo;
        Xhi[0] = *(const bf16x8*)(ringH + xb);
        Xhi[1] = *(const bf16x8*)(ringH + xb + 32);
        Xlo[0] = *(const bf16x8*)(ringL + xb);
        Xlo[1] = *(const bf16x8*)(ringL + xb + 32);
      }

      f32x4 aR  = {b_r, b_r, b_r, b_r};
      f32x4 aZ  = {b_z, b_z, b_z, b_z};
      f32x4 aHN = {0.f, 0.f, 0.f, 0.f};
      f32x4 aIN = {b_in, b_in, b_in, b_in};
      aR  = mm3(aR,  Ahi, Alo, Bh[0]);
      aZ  = mm3(aZ,  Ahi, Alo, Bh[1]);
      aHN = mm3(aHN, Ahi, Alo, Bh[2]);
      if (din1) {
#pragma unroll
        for (int q = 0; q < 4; ++q) {
          aR[q]  += xcur[q] * w_r;
          aZ[q]  += xcur[q] * w_z;
          aIN[q] += xcur[q] * w_n;
        }
        if (t + 1 < 512) {
          const float* xp = P.xseq + (size_t)row_base * 512 + (t + 1);
#pragma unroll
          for (int q = 0; q < 4; ++q) xcur[q] = xp[(size_t)(4 * q16 + q) * 512];
        }
      } else {
        aR  = mm2(aR,  Xhi, Xlo, Bx[0]);
        aZ  = mm2(aZ,  Xhi, Xlo, Bx[1]);
        aIN = mm2(aIN, Xhi, Xlo, Bx[2]);
      }

      // ---- activations + state + publish (slot t&3)
      unsigned short* wH = ringH + (g * 4 + (t & 3)) * 1152;
      unsigned short* wL = ringL + (g * 4 + (t & 3)) * 1152;
#pragma unroll
      for (int q = 0; q < 4; ++q) {
        float r = __builtin_amdgcn_rcpf(1.f + __expf(-aR[q]));
        float z = __builtin_amdgcn_rcpf(1.f + __expf(-aZ[q]));
        float na = aIN[q] + r * aHN[q];
        float e2 = __expf(2.f * na);
        float n  = __builtin_fmaf(-2.f, __builtin_amdgcn_rcpf(e2 + 1.f), 1.f);
        float h  = n + z * (hreg[q] - n);
        hreg[q] = h;
        if (cv) {
          const int idx = (4 * q16 + q) * 72 + pcw;
          unsigned short hb = f2bf(h);
          wH[idx] = hb;
          wL[idx] = f2bf(h - bfu2f(hb));
        }
      }
      if (!IS_DEC && t == 511 && cv) {
#pragma unroll
        for (int q = 0; q < 4; ++q)
          P.hfin_wr[((size_t)g * 2048 + row_base + 4 * q16 + q) * 64 + c] = hreg[q];
      }
    }

    // ---- publish progress (after all LDS ops of this step complete)
    asm volatile("s_waitcnt lgkmcnt(0)" ::: "memory");
    if (lane == 0) *((volatile unsigned*)&prog[4 * g + w]) = (unsigned)(t + 1);
  }
}

// ---------------------------------------------------------------------------
extern "C" void kernel_launch(void* const* d_in, const int* in_sizes, int n_in,
                              void* d_out, int out_size, void* d_ws, size_t ws_size,
                              hipStream_t stream) {
  (void)in_sizes; (void)n_in; (void)out_size; (void)ws_size;
  const float* inputs  = (const float*)d_in[0];
  const float* outputs = (const float*)d_in[1];

  unsigned short* frags = (unsigned short*)d_ws;             // 593920 B used
  float* hfin = (float*)((char*)d_ws + 655360);              // 1.5 MB

  static const int ofs[6]  = {2, 6, 10, 14, 18, 22};  // enc0,enc1,enc2,c1,c2,c3
  static const int dins[6] = {1, 60, 60, 1, 60, 60};

  PrepArgs pa;
  for (int ci = 0; ci < 6; ++ci) {
    pa.w[ci * 2 + 0]   = (const float*)d_in[ofs[ci] + 0];  // wih
    pa.w[ci * 2 + 1]   = (const float*)d_in[ofs[ci] + 1];  // whh
    pa.b[ci * 2 + 0]   = (const float*)d_in[ofs[ci] + 2];  // bih
    pa.b[ci * 2 + 1]   = (const float*)d_in[ofs[ci] + 3];  // bhh
    pa.din[ci * 2 + 0] = dins[ci];
    pa.din[ci * 2 + 1] = 60;
  }
  pa.w[12] = (const float*)d_in[26];                       // lin_w
  pa.b[12] = (const float*)d_in[27];                       // lin_b
  pa.din[12] = 60;
  pa.out = frags;
  prep_frags<<<dim3(1160), dim3(256), 0, stream>>>(pa);

  PhaseArgs ea;
  ea.xseq = inputs; ea.frags = frags;
  for (int gg = 0; gg < 3; ++gg) {
    ea.cell[gg].bih     = (const float*)d_in[ofs[gg] + 2];
    ea.cell[gg].wih_vec = (const float*)d_in[ofs[gg] + 0];
  }
  ea.hfin_rd = hfin; ea.hfin_wr = hfin;
  ea.lin_b = (const float*)d_in[27];
  ea.y = (float*)d_out;
  gru_phase<0><<<dim3(128), dim3(768), 0, stream>>>(ea);

  PhaseArgs da = ea;
  da.xseq = outputs;
  for (int gg = 0; gg < 3; ++gg) {
    da.cell[gg].bih     = (const float*)d_in[ofs[3 + gg] + 2];
    da.cell[gg].wih_vec = (const float*)d_in[ofs[3 + gg] + 0];
  }
  gru_phase<1><<<dim3(128), dim3(768), 0, stream>>>(da);
}

// Round 7
// 2442.208 us; speedup vs baseline: 1.2351x; 1.2351x over previous
//
#include <hip/hip_runtime.h>
#include <hip/hip_bf16.h>

// ============================================================================
// GRU seq2seq (3-layer enc + 3-cell dec + linear), B=2048, H=60, F=1, fp32.
//
// Round 7 = round 2 structure (best, 865us/phase) + three surgical fixes:
//  - XOR col swizzle c_phys = c ^ ((row>>2)<<4) on the LDS ring (stride 72):
//    kills the 4-way ds_write_b16 bank conflicts (318 cy/step measured).
//    Per-lane constant on both sides (write: row>>2 == q16; read: row == c16).
//  - Decoder y via 4-MFMA on g0w0 (reads h2_{s-3} from ring; lin_w bf16-hi
//    B-fragment from prep) -- removes 64 ds-shuffle ops/step (4 g2 waves).
//  - Step loop unrolled x2 (parity addressing loop-invariant); clamp-free
//    tanh n = 1 - 2*rcp(e2+1); lgkmcnt-only barrier.
//  - Kept: 128 blocks x 16 rows, 12 waves, hi/lo bf16 ring planes, mm3 h-path
//    mm2 x-path, AGPR-resident weights, x prefetch, launch_bounds(768,3).
// ============================================================================

typedef float  f32x4  __attribute__((ext_vector_type(4)));
typedef short  bf16x8 __attribute__((ext_vector_type(8)));

struct CellB  { const float* bih; const float* bhh; const float* wih_vec; };
struct PhaseArgs {
  const float* xseq;          // [2048][512] fp32
  const unsigned short* frags;
  CellB cell[3];
  const float* hfin_rd;       // dec: [3][2048][64] fp32
  float* hfin_wr;             // enc
  const float* lin_b;         // [1]
  float* y;                   // [2048][512]
};
struct PrepArgs {
  const float* w[13];         // (wih,whh) x 6 cells, then lin_w
  int din[13];
  unsigned short* out;
};

__device__ __forceinline__ unsigned int rne16(float x) {
  unsigned int u = __float_as_uint(x);
  return (u + 0x7fffu + ((u >> 16) & 1u)) >> 16;   // RNE bf16
}
__device__ __forceinline__ float bf2f(unsigned int b) { return __uint_as_float(b << 16); }
union BU { __hip_bfloat16 b; unsigned short u; };
__device__ __forceinline__ unsigned short f2bf(float x) { BU c; c.b = __float2bfloat16(x); return c.u; }
__device__ __forceinline__ float bfu2f(unsigned short s) { BU c; c.u = s; return __bfloat162float(c.b); }
__device__ __forceinline__ void wg_barrier() {
  asm volatile("s_waitcnt lgkmcnt(0)" ::: "memory");
  __builtin_amdgcn_s_barrier();
}

// ---------------------------------------------------------------------------
// Prep: B-fragments (bf16 hi/lo) for 6 cells x {wih,whh} (cm 0..11) and
// lin_w (cm 12, tile 0, col 0). frag_idx = (cm*12+tile)*4 + s2*2 + sp;
// short off = frag_idx*512 + lane*8 + e.
// element: col c = tile*16+(lane&15); k = s2*32+(lane>>4)*8+e.
// ---------------------------------------------------------------------------
__global__ void prep_frags(PrepArgs P) {
  int id = blockIdx.x * 256 + threadIdx.x;       // 1248*256 = 319488
  int e    = id & 7;
  int lane = (id >> 3) & 63;
  int sp   = (id >> 9) & 1;
  int s2   = (id >> 10) & 1;
  int rest = id >> 11;
  int tile = rest % 12;
  int cm   = rest / 12;
  if (cm > 12) return;
  const float* W = P.w[cm];
  int din = P.din[cm];
  int c = tile * 16 + (lane & 15);
  int k = s2 * 32 + (lane >> 4) * 8 + e;
  float v = 0.f;
  if (cm == 12) {
    if (c == 0 && k < 60) v = W[k];              // lin_w row
  } else {
    int j = c & 63, sec = c >> 6;
    if (j < 60 && k < din) v = W[(sec * 60 + j) * din + k];
  }
  unsigned int hi = rne16(v);
  unsigned short o = (unsigned short)(sp ? rne16(v - bf2f(hi)) : hi);
  P.out[id] = o;
}

// 3-product (hi*Whi + lo*Whi + hi*Wlo), two independent 3-deep chains
__device__ __forceinline__ f32x4 mm3(f32x4 acc, const bf16x8 Ahi[2],
                                     const bf16x8 Alo[2], const bf16x8 B[2][2]) {
  f32x4 a2 = {0.f, 0.f, 0.f, 0.f};
  acc = __builtin_amdgcn_mfma_f32_16x16x32_bf16(Ahi[0], B[0][0], acc, 0, 0, 0);
  a2  = __builtin_amdgcn_mfma_f32_16x16x32_bf16(Alo[0], B[0][0], a2,  0, 0, 0);
  acc = __builtin_amdgcn_mfma_f32_16x16x32_bf16(Ahi[1], B[1][0], acc, 0, 0, 0);
  a2  = __builtin_amdgcn_mfma_f32_16x16x32_bf16(Alo[1], B[1][0], a2,  0, 0, 0);
  acc = __builtin_amdgcn_mfma_f32_16x16x32_bf16(Ahi[0], B[0][1], acc, 0, 0, 0);
  a2  = __builtin_amdgcn_mfma_f32_16x16x32_bf16(Ahi[1], B[1][1], a2,  0, 0, 0);
  return acc + a2;
}
// 2-product (hi*Whi + lo*Whi)
__device__ __forceinline__ f32x4 mm2(f32x4 acc, const bf16x8 Ahi[2],
                                     const bf16x8 Alo[2], const bf16x8 B[2]) {
  f32x4 a2 = {0.f, 0.f, 0.f, 0.f};
  acc = __builtin_amdgcn_mfma_f32_16x16x32_bf16(Ahi[0], B[0], acc, 0, 0, 0);
  a2  = __builtin_amdgcn_mfma_f32_16x16x32_bf16(Alo[0], B[0], a2,  0, 0, 0);
  acc = __builtin_amdgcn_mfma_f32_16x16x32_bf16(Ahi[1], B[1], acc, 0, 0, 0);
  a2  = __builtin_amdgcn_mfma_f32_16x16x32_bf16(Alo[1], B[1], a2,  0, 0, 0);
  return acc + a2;
}

// ---------------------------------------------------------------------------
// Ring layout: [region 0..5][row 0..15][colPhys 0..71] shorts, region = g*2+par.
// element (row r, logical col c) at r*72 + (c ^ ((r>>2)<<4)).
// Step body macro: SPAR = s&1 (compile-time literal per copy).
// ---------------------------------------------------------------------------
#define GRU_STEP(SPAR, SV)                                                     \
  do {                                                                         \
    const int s_ = (SV);                                                       \
    if (yduty && s_ >= 3) {                                                    \
      const unsigned short* ybH = ringH + ((SPAR) ? 4 : 5) * 1152;             \
      const unsigned short* ybL = ringL + ((SPAR) ? 4 : 5) * 1152;             \
      bf16x8 Yhi[2], Ylo[2];                                                   \
      Yhi[0] = *(const bf16x8*)(ybH + ro0);                                    \
      Yhi[1] = *(const bf16x8*)(ybH + ro1);                                    \
      Ylo[0] = *(const bf16x8*)(ybL + ro0);                                    \
      Ylo[1] = *(const bf16x8*)(ybL + ro1);                                    \
      f32x4 ya = {lb, lb, lb, lb};                                             \
      ya = mm2(ya, Yhi, Ylo, Lw);                                              \
      if (c16 == 0) {                                                          \
        _Pragma("unroll")                                                      \
        for (int q = 0; q < 4; ++q)                                            \
          P.y[(size_t)(row_base + 4 * q16 + q) * 512 + (s_ - 3)] = ya[q];      \
      }                                                                        \
    }                                                                          \
    const int t_ = s_ - g;                                                     \
    if (t_ >= 0 && t_ < 512) {                                                 \
      const int oR_ = (SPAR) ? oRo : oRe;                                      \
      const int oW_ = (SPAR) ? oWo : oWe;                                      \
      const int oX_ = (SPAR) ? oXo : oXe;                                      \
      bf16x8 Ahi[2], Alo[2];                                                   \
      Ahi[0] = *(const bf16x8*)(ringH + oR_ + ro0);                            \
      Ahi[1] = *(const bf16x8*)(ringH + oR_ + ro1);                            \
      Alo[0] = *(const bf16x8*)(ringL + oR_ + ro0);                            \
      Alo[1] = *(const bf16x8*)(ringL + oR_ + ro1);                            \
      bf16x8 Xhi[2], Xlo[2];                                                   \
      if (!din1) {                                                             \
        Xhi[0] = *(const bf16x8*)(ringH + oX_ + ro0);                          \
        Xhi[1] = *(const bf16x8*)(ringH + oX_ + ro1);                          \
        Xlo[0] = *(const bf16x8*)(ringL + oX_ + ro0);                          \
        Xlo[1] = *(const bf16x8*)(ringL + oX_ + ro1);                          \
      }                                                                        \
      f32x4 aR  = {b_r, b_r, b_r, b_r};                                        \
      f32x4 aZ  = {b_z, b_z, b_z, b_z};                                        \
      f32x4 aHN = {b_hn, b_hn, b_hn, b_hn};                                    \
      f32x4 aIN = {b_in, b_in, b_in, b_in};                                    \
      aR  = mm3(aR,  Ahi, Alo, Bh[0]);                                         \
      aZ  = mm3(aZ,  Ahi, Alo, Bh[1]);                                         \
      aHN = mm3(aHN, Ahi, Alo, Bh[2]);                                         \
      if (din1) {                                                              \
        _Pragma("unroll")                                                      \
        for (int q = 0; q < 4; ++q) {                                          \
          aR[q]  += xcur[q] * w_r;                                             \
          aZ[q]  += xcur[q] * w_z;                                             \
          aIN[q] += xcur[q] * w_n;                                             \
        }                                                                      \
        if (t_ + 1 < 512) {                                                    \
          const float* xp_ = P.xseq + (size_t)row_base * 512 + (t_ + 1);       \
          _Pragma("unroll")                                                    \
          for (int q = 0; q < 4; ++q) xcur[q] = xp_[(size_t)(4 * q16 + q) * 512]; \
        }                                                                      \
      } else {                                                                 \
        aR  = mm2(aR,  Xhi, Xlo, Bx[0]);                                       \
        aZ  = mm2(aZ,  Xhi, Xlo, Bx[1]);                                       \
        aIN = mm2(aIN, Xhi, Xlo, Bx[2]);                                       \
      }                                                                        \
      unsigned short* wH_ = ringH + oW_;                                       \
      unsigned short* wL_ = ringL + oW_;                                       \
      _Pragma("unroll")                                                        \
      for (int q = 0; q < 4; ++q) {                                            \
        float r_ = __builtin_amdgcn_rcpf(1.f + __expf(-aR[q]));                \
        float z_ = __builtin_amdgcn_rcpf(1.f + __expf(-aZ[q]));                \
        float na = aIN[q] + r_ * aHN[q];                                       \
        float e2 = __expf(2.f * na);                                           \
        float n_ = __builtin_fmaf(-2.f, __builtin_amdgcn_rcpf(e2 + 1.f), 1.f); \
        float h_ = n_ + z_ * (hreg[q] - n_);                                   \
        hreg[q] = h_;                                                          \
        unsigned short hb_ = f2bf(h_);                                         \
        wH_[wo[q]] = hb_;                                                      \
        wL_[wo[q]] = f2bf(h_ - bfu2f(hb_));                                    \
      }                                                                        \
      if (!IS_DEC && t_ == 511 && cv) {                                        \
        _Pragma("unroll")                                                      \
        for (int q = 0; q < 4; ++q)                                            \
          P.hfin_wr[((size_t)g * 2048 + row_base + 4 * q16 + q) * 64 + c] =    \
              hreg[q];                                                         \
      }                                                                        \
    }                                                                          \
    wg_barrier();                                                              \
  } while (0)

template <int IS_DEC>
__global__ __launch_bounds__(768, 3) void gru_phase(PhaseArgs P) {
  __shared__ alignas(16) unsigned short ringH[6 * 16 * 72];
  __shared__ alignas(16) unsigned short ringL[6 * 16 * 72];

  const int tid  = threadIdx.x;
  const int lane = tid & 63;
  const int wid  = tid >> 6;
  const int g    = wid >> 2;      // layer/cell 0..2
  const int w    = wid & 3;       // col-tile 0..3
  const int c16  = lane & 15;
  const int q16  = lane >> 4;
  const int row_base = blockIdx.x * 16;
  const int c    = w * 16 + c16;  // logical h-col 0..63
  const bool cv  = (c < 60);
  const int cell = (IS_DEC ? 3 : 0) + g;
  const bool din1 = (g == 0);
  const bool yduty = (IS_DEC && g == 0 && w == 0);

  // swizzled per-lane LDS offsets (shorts)
  const int swzW = (w * 16 + c16) ^ (q16 << 4);
  int wo[4];
#pragma unroll
  for (int q = 0; q < 4; ++q) wo[q] = (4 * q16 + q) * 72 + swzW;
  const int ro0 = c16 * 72 + ((q16 * 8) ^ ((c16 >> 2) << 4));
  const int ro1 = c16 * 72 + ((32 + q16 * 8) ^ ((c16 >> 2) << 4));

  // region bases (shorts) by step parity
  const int gp   = g & 1;
  const int oWe = g * 2304 + gp * 1152;          // write region, s even
  const int oWo = g * 2304 + (gp ^ 1) * 1152;    // write region, s odd
  const int oRe = oWo;                           // own-read = opposite parity
  const int oRo = oWe;
  const int oXe = (g - 1) * 2304 + gp * 1152;    // x-read (valid g>0)
  const int oXo = (g - 1) * 2304 + (gp ^ 1) * 1152;

  // per-lane constants
  const float* bih = P.cell[g].bih;
  const float* bhh = P.cell[g].bhh;
  float b_r  = cv ? bih[c] + bhh[c]           : 0.f;
  float b_z  = cv ? bih[60 + c] + bhh[60 + c] : 0.f;
  float b_hn = cv ? bhh[120 + c]              : 0.f;
  float b_in = cv ? bih[120 + c]              : 0.f;
  float w_r = 0.f, w_z = 0.f, w_n = 0.f;
  if (din1 && cv) {
    const float* wv = P.cell[g].wih_vec;
    w_r = wv[c]; w_z = wv[60 + c]; w_n = wv[120 + c];
  }
  float lb = 0.f;
  if (yduty) lb = P.lin_b[0];

  // persistent weight fragments (AGPR-eligible)
  bf16x8 Bh[3][2][2], Bx[3][2], Lw[2];
#pragma unroll
  for (int T = 0; T < 3; ++T)
#pragma unroll
    for (int s2 = 0; s2 < 2; ++s2) {
      const int tile = w + 4 * T;
#pragma unroll
      for (int sp = 0; sp < 2; ++sp)
        Bh[T][s2][sp] = *(const bf16x8*)(P.frags +
            (size_t)(((cell * 2 + 1) * 12 + tile) * 4 + s2 * 2 + sp) * 512 + lane * 8);
      Bx[T][s2] = *(const bf16x8*)(P.frags +
          (size_t)(((cell * 2 + 0) * 12 + tile) * 4 + s2 * 2 + 0) * 512 + lane * 8);
    }
#pragma unroll
  for (int s2 = 0; s2 < 2; ++s2)
    Lw[s2] = *(const bf16x8*)(P.frags +
        (size_t)((12 * 12 + 0) * 4 + s2 * 2 + 0) * 512 + lane * 8);

  // h0 init (enc: zeros; dec: encoder final h) into own-read region of t=0
  float hreg[4];
#pragma unroll
  for (int q = 0; q < 4; ++q) {
    float h0 = 0.f;
    if (IS_DEC && cv)
      h0 = P.hfin_rd[((size_t)(2 - g) * 2048 + row_base + 4 * q16 + q) * 64 + c];
    hreg[q] = h0;
    unsigned short hb = f2bf(h0);
    ringH[g * 2304 + 1152 + wo[q]] = hb;
    ringL[g * 2304 + 1152 + wo[q]] = f2bf(h0 - bfu2f(hb));
  }

  float xcur[4] = {0.f, 0.f, 0.f, 0.f};
  if (din1) {
    const float* xp = P.xseq + (size_t)row_base * 512;
#pragma unroll
    for (int q = 0; q < 4; ++q) xcur[q] = xp[(size_t)(4 * q16 + q) * 512];
  }
  wg_barrier();

#pragma unroll 1
  for (int sb = 0; sb < 514; sb += 2) {
    GRU_STEP(0, sb);
    GRU_STEP(1, sb + 1);
  }

  // decoder epilogue: y_{511} (h2_511 written in slot 513, barrier passed)
  if (IS_DEC && yduty) {
    const unsigned short* ybH = ringH + 5 * 1152;   // parity 511&1 = 1
    const unsigned short* ybL = ringL + 5 * 1152;
    bf16x8 Yhi[2], Ylo[2];
    Yhi[0] = *(const bf16x8*)(ybH + ro0);
    Yhi[1] = *(const bf16x8*)(ybH + ro1);
    Ylo[0] = *(const bf16x8*)(ybL + ro0);
    Ylo[1] = *(const bf16x8*)(ybL + ro1);
    f32x4 ya = {lb, lb, lb, lb};
    ya = mm2(ya, Yhi, Ylo, Lw);
    if (c16 == 0) {
#pragma unroll
      for (int q = 0; q < 4; ++q)
        P.y[(size_t)(row_base + 4 * q16 + q) * 512 + 511] = ya[q];
    }
  }
}

// ---------------------------------------------------------------------------
extern "C" void kernel_launch(void* const* d_in, const int* in_sizes, int n_in,
                              void* d_out, int out_size, void* d_ws, size_t ws_size,
                              hipStream_t stream) {
  (void)in_sizes; (void)n_in; (void)out_size; (void)ws_size;
  const float* inputs  = (const float*)d_in[0];
  const float* outputs = (const float*)d_in[1];

  unsigned short* frags = (unsigned short*)d_ws;            // 638976 B
  float* hfin = (float*)((char*)d_ws + 655360);             // 1.5 MB

  static const int ofs[6]  = {2, 6, 10, 14, 18, 22};  // enc0,enc1,enc2,c1,c2,c3
  static const int dins[6] = {1, 60, 60, 1, 60, 60};

  PrepArgs pa;
  for (int ci = 0; ci < 6; ++ci) {
    pa.w[ci * 2 + 0]   = (const float*)d_in[ofs[ci] + 0];  // wih
    pa.w[ci * 2 + 1]   = (const float*)d_in[ofs[ci] + 1];  // whh
    pa.din[ci * 2 + 0] = dins[ci];
    pa.din[ci * 2 + 1] = 60;
  }
  pa.w[12]   = (const float*)d_in[26];                     // lin_w
  pa.din[12] = 60;
  pa.out = frags;
  prep_frags<<<dim3(1248), dim3(256), 0, stream>>>(pa);

  PhaseArgs ea;
  ea.xseq = inputs; ea.frags = frags;
  for (int gg = 0; gg < 3; ++gg) {
    ea.cell[gg].bih     = (const float*)d_in[ofs[gg] + 2];
    ea.cell[gg].bhh     = (const float*)d_in[ofs[gg] + 3];
    ea.cell[gg].wih_vec = (const float*)d_in[ofs[gg] + 0];
  }
  ea.hfin_rd = hfin; ea.hfin_wr = hfin;
  ea.lin_b = (const float*)d_in[27];
  ea.y = (float*)d_out;
  gru_phase<0><<<dim3(128), dim3(768), 0, stream>>>(ea);

  PhaseArgs da = ea;
  da.xseq = outputs;
  for (int gg = 0; gg < 3; ++gg) {
    da.cell[gg].bih     = (const float*)d_in[ofs[3 + gg] + 2];
    da.cell[gg].bhh     = (const float*)d_in[ofs[3 + gg] + 3];
    da.cell[gg].wih_vec = (const float*)d_in[ofs[3 + gg] + 0];
  }
  gru_phase<1><<<dim3(128), dim3(768), 0, stream>>>(da);
}

// Round 8
// 1497.458 us; speedup vs baseline: 2.0143x; 1.6309x over previous
//
#include <hip/hip_runtime.h>
#include <hip/hip_bf16.h>

// ============================================================================
// GRU seq2seq (3-layer enc + 3-cell dec + linear), B=2048, H=60, F=1, fp32.
//
// Round 8 = round 2 structure (best, 865us/phase) + audited deltas:
//  - Ring row stride 72 -> 88 shorts: write banks 16q16+12q+8w+c16/2 -> <=2-way
//    (free); read base 12c16+4q16 same class as r2's empirically-clean reads.
//    (r2's 318 cy/step conflicts were the ds_write_b16's 4-way aliasing.)
//  - Decoder y via MFMA on g0w0 (lin_w bf16-hi B-frag): removes 64 shfl DS ops
//    per step. Lw only under IS_DEC.
//  - Clamp-free tanh: n = 1 - 2*rcp(e2+1)  (exact at +-inf).
//  - Kept from r2: 128 blocks x 16 rows, 12 waves (4/group), hi/lo bf16 ring
//    planes, mm3 h-path / mm2 x-path split chains, reg-resident weights,
//    x prefetch, lgkmcnt-only barrier, launch_bounds(768,3). No unrolling.
// ============================================================================

typedef float  f32x4  __attribute__((ext_vector_type(4)));
typedef short  bf16x8 __attribute__((ext_vector_type(8)));

#define RSTR 88               // ring row stride in shorts (16B-aligned rows)
#define REG  (16 * RSTR)      // shorts per region

struct CellB  { const float* bih; const float* bhh; const float* wih_vec; };
struct PhaseArgs {
  const float* xseq;          // [2048][512] fp32
  const unsigned short* frags;
  CellB cell[3];
  const float* hfin_rd;       // dec: [3][2048][64] fp32
  float* hfin_wr;             // enc
  const float* lin_b;         // [1]
  float* y;                   // [2048][512]
};
struct PrepArgs {
  const float* w[13];         // (wih,whh) x 6 cells, then lin_w
  int din[13];
  unsigned short* out;
};

__device__ __forceinline__ unsigned int rne16(float x) {
  unsigned int u = __float_as_uint(x);
  return (u + 0x7fffu + ((u >> 16) & 1u)) >> 16;   // RNE bf16
}
__device__ __forceinline__ float bf2f(unsigned int b) { return __uint_as_float(b << 16); }
union BU { __hip_bfloat16 b; unsigned short u; };
__device__ __forceinline__ unsigned short f2bf(float x) { BU c; c.b = __float2bfloat16(x); return c.u; }
__device__ __forceinline__ float bfu2f(unsigned short s) { BU c; c.u = s; return __bfloat162float(c.b); }
__device__ __forceinline__ void wg_barrier() {
  asm volatile("s_waitcnt lgkmcnt(0)" ::: "memory");
  __builtin_amdgcn_s_barrier();
}

// ---------------------------------------------------------------------------
// Prep: B-fragments (bf16 hi/lo) for 6 cells x {wih,whh} (cm 0..11) and
// lin_w (cm 12, tile 0, col 0). frag_idx = (cm*12+tile)*4 + s2*2 + sp;
// short off = frag_idx*512 + lane*8 + e.
// element: col c = tile*16+(lane&15); k = s2*32+(lane>>4)*8+e.
// ---------------------------------------------------------------------------
__global__ void prep_frags(PrepArgs P) {
  int id = blockIdx.x * 256 + threadIdx.x;       // 1248*256 = 319488
  int e    = id & 7;
  int lane = (id >> 3) & 63;
  int sp   = (id >> 9) & 1;
  int s2   = (id >> 10) & 1;
  int rest = id >> 11;
  int tile = rest % 12;
  int cm   = rest / 12;
  if (cm > 12) return;
  const float* W = P.w[cm];
  int din = P.din[cm];
  int c = tile * 16 + (lane & 15);
  int k = s2 * 32 + (lane >> 4) * 8 + e;
  float v = 0.f;
  if (cm == 12) {
    if (c == 0 && k < 60) v = W[k];              // lin_w row
  } else {
    int j = c & 63, sec = c >> 6;
    if (j < 60 && k < din) v = W[(sec * 60 + j) * din + k];
  }
  unsigned int hi = rne16(v);
  unsigned short o = (unsigned short)(sp ? rne16(v - bf2f(hi)) : hi);
  P.out[id] = o;
}

// 3-product (hi*Whi + lo*Whi + hi*Wlo), two independent 3-deep chains
__device__ __forceinline__ f32x4 mm3(f32x4 acc, const bf16x8 Ahi[2],
                                     const bf16x8 Alo[2], const bf16x8 B[2][2]) {
  f32x4 a2 = {0.f, 0.f, 0.f, 0.f};
  acc = __builtin_amdgcn_mfma_f32_16x16x32_bf16(Ahi[0], B[0][0], acc, 0, 0, 0);
  a2  = __builtin_amdgcn_mfma_f32_16x16x32_bf16(Alo[0], B[0][0], a2,  0, 0, 0);
  acc = __builtin_amdgcn_mfma_f32_16x16x32_bf16(Ahi[1], B[1][0], acc, 0, 0, 0);
  a2  = __builtin_amdgcn_mfma_f32_16x16x32_bf16(Alo[1], B[1][0], a2,  0, 0, 0);
  acc = __builtin_amdgcn_mfma_f32_16x16x32_bf16(Ahi[0], B[0][1], acc, 0, 0, 0);
  a2  = __builtin_amdgcn_mfma_f32_16x16x32_bf16(Ahi[1], B[1][1], a2,  0, 0, 0);
  return acc + a2;
}
// 2-product (hi*Whi + lo*Whi), two independent 2-deep chains
__device__ __forceinline__ f32x4 mm2(f32x4 acc, const bf16x8 Ahi[2],
                                     const bf16x8 Alo[2], const bf16x8 B[2]) {
  f32x4 a2 = {0.f, 0.f, 0.f, 0.f};
  acc = __builtin_amdgcn_mfma_f32_16x16x32_bf16(Ahi[0], B[0], acc, 0, 0, 0);
  a2  = __builtin_amdgcn_mfma_f32_16x16x32_bf16(Alo[0], B[0], a2,  0, 0, 0);
  acc = __builtin_amdgcn_mfma_f32_16x16x32_bf16(Ahi[1], B[1], acc, 0, 0, 0);
  a2  = __builtin_amdgcn_mfma_f32_16x16x32_bf16(Alo[1], B[1], a2,  0, 0, 0);
  return acc + a2;
}

// ---------------------------------------------------------------------------
// Fused 3-stage GRU pipeline. IS_DEC=0: encoder; IS_DEC=1: decoder (+linear).
// Ring: [region 0..5][row 0..15][col 0..63 of RSTR] shorts; region = g*2+par.
// ---------------------------------------------------------------------------
template <int IS_DEC>
__global__ __launch_bounds__(768, 3) void gru_phase(PhaseArgs P) {
  __shared__ alignas(16) unsigned short ringH[6 * REG];
  __shared__ alignas(16) unsigned short ringL[6 * REG];

  const int tid  = threadIdx.x;
  const int lane = tid & 63;
  const int wid  = tid >> 6;
  const int g    = wid >> 2;      // layer/cell 0..2
  const int w    = wid & 3;       // col-tile 0..3
  const int c16  = lane & 15;
  const int q16  = lane >> 4;
  const int row_base = blockIdx.x * 16;
  const int c    = w * 16 + c16;  // logical h-col 0..63
  const bool cv  = (c < 60);
  const int cell = (IS_DEC ? 3 : 0) + g;
  const bool din1 = (g == 0);
  const bool yduty = (IS_DEC && g == 0 && w == 0);

  // per-lane LDS offsets (shorts)
  int wo[4];
#pragma unroll
  for (int q = 0; q < 4; ++q) wo[q] = (4 * q16 + q) * RSTR + c;
  const int ro0 = c16 * RSTR + q16 * 8;
  const int ro1 = ro0 + 32;

  // per-lane constants
  const float* bih = P.cell[g].bih;
  const float* bhh = P.cell[g].bhh;
  float b_r  = cv ? bih[c] + bhh[c]           : 0.f;
  float b_z  = cv ? bih[60 + c] + bhh[60 + c] : 0.f;
  float b_hn = cv ? bhh[120 + c]              : 0.f;
  float b_in = cv ? bih[120 + c]              : 0.f;
  float w_r = 0.f, w_z = 0.f, w_n = 0.f;
  if (din1 && cv) {
    const float* wv = P.cell[g].wih_vec;
    w_r = wv[c]; w_z = wv[60 + c]; w_n = wv[120 + c];
  }

  // persistent weight fragments
  bf16x8 Bh[3][2][2], Bx[3][2];
#pragma unroll
  for (int T = 0; T < 3; ++T)
#pragma unroll
    for (int s2 = 0; s2 < 2; ++s2) {
      const int tile = w + 4 * T;
#pragma unroll
      for (int sp = 0; sp < 2; ++sp)
        Bh[T][s2][sp] = *(const bf16x8*)(P.frags +
            (size_t)(((cell * 2 + 1) * 12 + tile) * 4 + s2 * 2 + sp) * 512 + lane * 8);
      Bx[T][s2] = *(const bf16x8*)(P.frags +
          (size_t)(((cell * 2 + 0) * 12 + tile) * 4 + s2 * 2 + 0) * 512 + lane * 8);
    }
  bf16x8 Lw[2];
  float lb = 0.f;
  if (IS_DEC) {
    lb = P.lin_b[0];
#pragma unroll
    for (int s2 = 0; s2 < 2; ++s2)
      Lw[s2] = *(const bf16x8*)(P.frags +
          (size_t)((12 * 12 + 0) * 4 + s2 * 2 + 0) * 512 + lane * 8);
  }

  // h0 (enc: zeros; dec: encoder final h) into parity-1 region (read slot t=0)
  float hreg[4];
#pragma unroll
  for (int q = 0; q < 4; ++q) {
    float h0 = 0.f;
    if (IS_DEC && cv)
      h0 = P.hfin_rd[((size_t)(2 - g) * 2048 + row_base + 4 * q16 + q) * 64 + c];
    hreg[q] = h0;
    unsigned short hb = f2bf(h0);
    ringH[(g * 2 + 1) * REG + wo[q]] = hb;
    ringL[(g * 2 + 1) * REG + wo[q]] = f2bf(h0 - bfu2f(hb));
  }

  // x prefetch (t=0) for g0
  float xcur[4] = {0.f, 0.f, 0.f, 0.f};
  if (din1) {
    const float* xp = P.xseq + (size_t)row_base * 512;
#pragma unroll
    for (int q = 0; q < 4; ++q) xcur[q] = xp[(size_t)(4 * q16 + q) * 512];
  }
  wg_barrier();

#pragma unroll 1
  for (int s = 0; s < 514; ++s) {
    // decoder y_{s-3} = h2_{s-3} @ lin_w + lin_b (MFMA on g0w0)
    if (yduty && s >= 3) {
      const int yb = (4 + ((s + 1) & 1)) * REG;
      bf16x8 Yhi[2], Ylo[2];
      Yhi[0] = *(const bf16x8*)(ringH + yb + ro0);
      Yhi[1] = *(const bf16x8*)(ringH + yb + ro1);
      Ylo[0] = *(const bf16x8*)(ringL + yb + ro0);
      Ylo[1] = *(const bf16x8*)(ringL + yb + ro1);
      f32x4 ya = {lb, lb, lb, lb};
      ya = mm2(ya, Yhi, Ylo, Lw);
      if (c16 == 0) {
#pragma unroll
        for (int q = 0; q < 4; ++q)
          P.y[(size_t)(row_base + 4 * q16 + q) * 512 + (s - 3)] = ya[q];
      }
    }

    const int t = s - g;
    if (t >= 0 && t < 512) {
      // ---- A loads up front
      const int oR = (g * 2 + ((t + 1) & 1)) * REG;
      bf16x8 Ahi[2], Alo[2];
      Ahi[0] = *(const bf16x8*)(ringH + oR + ro0);
      Ahi[1] = *(const bf16x8*)(ringH + oR + ro1);
      Alo[0] = *(const bf16x8*)(ringL + oR + ro0);
      Alo[1] = *(const bf16x8*)(ringL + oR + ro1);
      bf16x8 Xhi[2], Xlo[2];
      if (!din1) {
        const int oX = ((g - 1) * 2 + (t & 1)) * REG;
        Xhi[0] = *(const bf16x8*)(ringH + oX + ro0);
        Xhi[1] = *(const bf16x8*)(ringH + oX + ro1);
        Xlo[0] = *(const bf16x8*)(ringL + oX + ro0);
        Xlo[1] = *(const bf16x8*)(ringL + oX + ro1);
      }

      f32x4 aR  = {b_r, b_r, b_r, b_r};
      f32x4 aZ  = {b_z, b_z, b_z, b_z};
      f32x4 aHN = {b_hn, b_hn, b_hn, b_hn};
      f32x4 aIN = {b_in, b_in, b_in, b_in};
      aR  = mm3(aR,  Ahi, Alo, Bh[0]);
      aZ  = mm3(aZ,  Ahi, Alo, Bh[1]);
      aHN = mm3(aHN, Ahi, Alo, Bh[2]);

      if (din1) {
#pragma unroll
        for (int q = 0; q < 4; ++q) {
          aR[q]  += xcur[q] * w_r;
          aZ[q]  += xcur[q] * w_z;
          aIN[q] += xcur[q] * w_n;
        }
        if (t + 1 < 512) {                      // prefetch next step's x
          const float* xp = P.xseq + (size_t)row_base * 512 + (t + 1);
#pragma unroll
          for (int q = 0; q < 4; ++q) xcur[q] = xp[(size_t)(4 * q16 + q) * 512];
        }
      } else {
        aR  = mm2(aR,  Xhi, Xlo, Bx[0]);
        aZ  = mm2(aZ,  Xhi, Xlo, Bx[1]);
        aIN = mm2(aIN, Xhi, Xlo, Bx[2]);
      }

      // ---- activations + state update (full fp32), publish to parity t&1
      unsigned short* wH = ringH + (g * 2 + (t & 1)) * REG;
      unsigned short* wL = ringL + (g * 2 + (t & 1)) * REG;
#pragma unroll
      for (int q = 0; q < 4; ++q) {
        float r = __builtin_amdgcn_rcpf(1.f + __expf(-aR[q]));
        float z = __builtin_amdgcn_rcpf(1.f + __expf(-aZ[q]));
        float na = aIN[q] + r * aHN[q];
        float e2 = __expf(2.f * na);
        float n  = __builtin_fmaf(-2.f, __builtin_amdgcn_rcpf(e2 + 1.f), 1.f);
        float h  = n + z * (hreg[q] - n);
        hreg[q]  = h;
        unsigned short hb = f2bf(h);
        wH[wo[q]] = hb;
        wL[wo[q]] = f2bf(h - bfu2f(hb));
      }

      // ---- encoder: store final hidden state
      if (!IS_DEC && t == 511) {
#pragma unroll
        for (int q = 0; q < 4; ++q)
          P.hfin_wr[((size_t)g * 2048 + row_base + 4 * q16 + q) * 64 + c] = hreg[q];
      }
    }
    wg_barrier();
  }

  // decoder epilogue: y_511 (h2_511 written at s=513 into region 5)
  if (yduty) {
    const int yb = 5 * REG;
    bf16x8 Yhi[2], Ylo[2];
    Yhi[0] = *(const bf16x8*)(ringH + yb + ro0);
    Yhi[1] = *(const bf16x8*)(ringH + yb + ro1);
    Ylo[0] = *(const bf16x8*)(ringL + yb + ro0);
    Ylo[1] = *(const bf16x8*)(ringL + yb + ro1);
    f32x4 ya = {lb, lb, lb, lb};
    ya = mm2(ya, Yhi, Ylo, Lw);
    if (c16 == 0) {
#pragma unroll
      for (int q = 0; q < 4; ++q)
        P.y[(size_t)(row_base + 4 * q16 + q) * 512 + 511] = ya[q];
    }
  }
}

// ---------------------------------------------------------------------------
extern "C" void kernel_launch(void* const* d_in, const int* in_sizes, int n_in,
                              void* d_out, int out_size, void* d_ws, size_t ws_size,
                              hipStream_t stream) {
  (void)in_sizes; (void)n_in; (void)out_size; (void)ws_size;
  const float* inputs  = (const float*)d_in[0];
  const float* outputs = (const float*)d_in[1];

  unsigned short* frags = (unsigned short*)d_ws;            // 638976 B
  float* hfin = (float*)((char*)d_ws + 655360);             // 1.5 MB

  static const int ofs[6]  = {2, 6, 10, 14, 18, 22};  // enc0,enc1,enc2,c1,c2,c3
  static const int dins[6] = {1, 60, 60, 1, 60, 60};

  PrepArgs pa;
  for (int ci = 0; ci < 6; ++ci) {
    pa.w[ci * 2 + 0]   = (const float*)d_in[ofs[ci] + 0];  // wih
    pa.w[ci * 2 + 1]   = (const float*)d_in[ofs[ci] + 1];  // whh
    pa.din[ci * 2 + 0] = dins[ci];
    pa.din[ci * 2 + 1] = 60;
  }
  pa.w[12]   = (const float*)d_in[26];                     // lin_w
  pa.din[12] = 60;
  pa.out = frags;
  prep_frags<<<dim3(1248), dim3(256), 0, stream>>>(pa);

  PhaseArgs ea;
  ea.xseq = inputs; ea.frags = frags;
  for (int gg = 0; gg < 3; ++gg) {
    ea.cell[gg].bih     = (const float*)d_in[ofs[gg] + 2];
    ea.cell[gg].bhh     = (const float*)d_in[ofs[gg] + 3];
    ea.cell[gg].wih_vec = (const float*)d_in[ofs[gg] + 0];
  }
  ea.hfin_rd = hfin; ea.hfin_wr = hfin;
  ea.lin_b = (const float*)d_in[27];
  ea.y = (float*)d_out;
  gru_phase<0><<<dim3(128), dim3(768), 0, stream>>>(ea);

  PhaseArgs da = ea;
  da.xseq = outputs;
  for (int gg = 0; gg < 3; ++gg) {
    da.cell[gg].bih     = (const float*)d_in[ofs[3 + gg] + 2];
    da.cell[gg].bhh     = (const float*)d_in[ofs[3 + gg] + 3];
    da.cell[gg].wih_vec = (const float*)d_in[ofs[3 + gg] + 0];
  }
  gru_phase<1><<<dim3(128), dim3(768), 0, stream>>>(da);
}

// Round 9
// 1168.844 us; speedup vs baseline: 2.5806x; 1.2811x over previous
//
#include <hip/hip_runtime.h>
#include <hip/hip_bf16.h>

// ============================================================================
// GRU seq2seq (3-layer enc + 3-cell dec + linear), B=2048, H=60, F=1, fp32.
//
// Round 9 = round 8 structure + f16 single-plane ring (halves LDS traffic):
//  - h stored as ONE f16 plane (|h|<1 -> 2^-12 abs err; was bf16 hi/lo pair).
//    A-loads 4->2 b128, X-loads 4->2, writes 8->4 b16 per wave per step.
//    LDS pipe ~1900 -> ~900 cy/step (the measured dominant pipe).
//  - Weights stay high-precision in regs: h-path A x (Whi + Wlo) f16 pairs
//    (lo = f16 residual), x-path A x Whi only. MFMA/wave 30 -> 18.
//  - h recurrence itself still full fp32 in registers; encoder->decoder
//    handoff (hfin) full fp32.
//  - Kept: 128 blocks x 16 rows, 12 waves (4/group), y via MFMA on g0w0,
//    x prefetch, lgkmcnt-only barrier, launch_bounds(768,3), no unroll.
// ============================================================================

typedef float    f32x4 __attribute__((ext_vector_type(4)));
typedef _Float16 f16x8 __attribute__((ext_vector_type(8)));

#define RSTR 72               // ring row stride in shorts (16B-aligned rows)
#define REG  (16 * RSTR)      // shorts per region

struct CellB  { const float* bih; const float* bhh; const float* wih_vec; };
struct PhaseArgs {
  const float* xseq;          // [2048][512] fp32
  const unsigned short* frags;
  CellB cell[3];
  const float* hfin_rd;       // dec: [3][2048][64] fp32
  float* hfin_wr;             // enc
  const float* lin_b;         // [1]
  float* y;                   // [2048][512]
};
struct PrepArgs {
  const float* w[13];         // (wih,whh) x 6 cells, then lin_w
  int din[13];
  unsigned short* out;
};

union HU { _Float16 h; unsigned short u; };
__device__ __forceinline__ unsigned short f2h(float x) { HU c; c.h = (_Float16)x; return c.u; }
__device__ __forceinline__ float h2f(unsigned short s) { HU c; c.u = s; return (float)c.h; }
__device__ __forceinline__ void wg_barrier() {
  asm volatile("s_waitcnt lgkmcnt(0)" ::: "memory");
  __builtin_amdgcn_s_barrier();
}

// ---------------------------------------------------------------------------
// Prep: f16 B-fragments (hi = f16(v), lo = f16(v - float(hi))) for 6 cells x
// {wih,whh} (cm 0..11) and lin_w (cm 12, tile 0, col 0).
// frag_idx = (cm*12+tile)*4 + s2*2 + sp; short off = frag_idx*512 + lane*8 + e.
// element: col c = tile*16+(lane&15); k = s2*32+(lane>>4)*8+e.
// ---------------------------------------------------------------------------
__global__ void prep_frags(PrepArgs P) {
  int id = blockIdx.x * 256 + threadIdx.x;       // 1248*256 = 319488
  int e    = id & 7;
  int lane = (id >> 3) & 63;
  int sp   = (id >> 9) & 1;
  int s2   = (id >> 10) & 1;
  int rest = id >> 11;
  int tile = rest % 12;
  int cm   = rest / 12;
  if (cm > 12) return;
  const float* W = P.w[cm];
  int din = P.din[cm];
  int c = tile * 16 + (lane & 15);
  int k = s2 * 32 + (lane >> 4) * 8 + e;
  float v = 0.f;
  if (cm == 12) {
    if (c == 0 && k < 60) v = W[k];              // lin_w row
  } else {
    int j = c & 63, sec = c >> 6;
    if (j < 60 && k < din) v = W[(sec * 60 + j) * din + k];
  }
  unsigned short hi = f2h(v);
  unsigned short o = sp ? f2h(v - h2f(hi)) : hi;
  P.out[id] = o;
}

// h-path: A x (Whi + Wlo), two independent 2-deep chains (4 MFMA)
__device__ __forceinline__ f32x4 mmh(f32x4 acc, const f16x8 A[2], const f16x8 B[2][2]) {
  f32x4 a2 = {0.f, 0.f, 0.f, 0.f};
  acc = __builtin_amdgcn_mfma_f32_16x16x32_f16(A[0], B[0][0], acc, 0, 0, 0);
  a2  = __builtin_amdgcn_mfma_f32_16x16x32_f16(A[0], B[0][1], a2,  0, 0, 0);
  acc = __builtin_amdgcn_mfma_f32_16x16x32_f16(A[1], B[1][0], acc, 0, 0, 0);
  a2  = __builtin_amdgcn_mfma_f32_16x16x32_f16(A[1], B[1][1], a2,  0, 0, 0);
  return acc + a2;
}
// x-path: A x Whi only (2 MFMA, one chain)
__device__ __forceinline__ f32x4 mmx(f32x4 acc, const f16x8 A[2], const f16x8 B[2]) {
  acc = __builtin_amdgcn_mfma_f32_16x16x32_f16(A[0], B[0], acc, 0, 0, 0);
  acc = __builtin_amdgcn_mfma_f32_16x16x32_f16(A[1], B[1], acc, 0, 0, 0);
  return acc;
}

// ---------------------------------------------------------------------------
// Fused 3-stage GRU pipeline. IS_DEC=0: encoder; IS_DEC=1: decoder (+linear).
// Ring: [region 0..5][row 0..15][col 0..63 of RSTR] f16; region = g*2+parity.
// ---------------------------------------------------------------------------
template <int IS_DEC>
__global__ __launch_bounds__(768, 3) void gru_phase(PhaseArgs P) {
  __shared__ alignas(16) unsigned short ring[6 * REG];

  const int tid  = threadIdx.x;
  const int lane = tid & 63;
  const int wid  = tid >> 6;
  const int g    = wid >> 2;      // layer/cell 0..2
  const int w    = wid & 3;       // col-tile 0..3
  const int c16  = lane & 15;
  const int q16  = lane >> 4;
  const int row_base = blockIdx.x * 16;
  const int c    = w * 16 + c16;  // logical h-col 0..63
  const bool cv  = (c < 60);
  const int cell = (IS_DEC ? 3 : 0) + g;
  const bool din1 = (g == 0);
  const bool yduty = (IS_DEC && g == 0 && w == 0);

  // per-lane LDS offsets (shorts)
  int wo[4];
#pragma unroll
  for (int q = 0; q < 4; ++q) wo[q] = (4 * q16 + q) * RSTR + c;
  const int ro0 = c16 * RSTR + q16 * 8;
  const int ro1 = ro0 + 32;

  // per-lane constants
  const float* bih = P.cell[g].bih;
  const float* bhh = P.cell[g].bhh;
  float b_r  = cv ? bih[c] + bhh[c]           : 0.f;
  float b_z  = cv ? bih[60 + c] + bhh[60 + c] : 0.f;
  float b_hn = cv ? bhh[120 + c]              : 0.f;
  float b_in = cv ? bih[120 + c]              : 0.f;
  float w_r = 0.f, w_z = 0.f, w_n = 0.f;
  if (din1 && cv) {
    const float* wv = P.cell[g].wih_vec;
    w_r = wv[c]; w_z = wv[60 + c]; w_n = wv[120 + c];
  }

  // persistent weight fragments: Bh hi/lo, Bx hi only
  f16x8 Bh[3][2][2], Bx[3][2];
#pragma unroll
  for (int T = 0; T < 3; ++T)
#pragma unroll
    for (int s2 = 0; s2 < 2; ++s2) {
      const int tile = w + 4 * T;
#pragma unroll
      for (int sp = 0; sp < 2; ++sp)
        Bh[T][s2][sp] = *(const f16x8*)(P.frags +
            (size_t)(((cell * 2 + 1) * 12 + tile) * 4 + s2 * 2 + sp) * 512 + lane * 8);
      Bx[T][s2] = *(const f16x8*)(P.frags +
          (size_t)(((cell * 2 + 0) * 12 + tile) * 4 + s2 * 2 + 0) * 512 + lane * 8);
    }
  f16x8 Lw[2][2];
  float lb = 0.f;
  if (IS_DEC) {
    lb = P.lin_b[0];
#pragma unroll
    for (int s2 = 0; s2 < 2; ++s2)
#pragma unroll
      for (int sp = 0; sp < 2; ++sp)
        Lw[s2][sp] = *(const f16x8*)(P.frags +
            (size_t)((12 * 12 + 0) * 4 + s2 * 2 + sp) * 512 + lane * 8);
  }

  // h0 (enc: zeros; dec: encoder final h) into parity-1 region (read slot t=0)
  float hreg[4];
#pragma unroll
  for (int q = 0; q < 4; ++q) {
    float h0 = 0.f;
    if (IS_DEC && cv)
      h0 = P.hfin_rd[((size_t)(2 - g) * 2048 + row_base + 4 * q16 + q) * 64 + c];
    hreg[q] = h0;
    ring[(g * 2 + 1) * REG + wo[q]] = f2h(h0);
  }

  // x prefetch (t=0) for g0
  float xcur[4] = {0.f, 0.f, 0.f, 0.f};
  if (din1) {
    const float* xp = P.xseq + (size_t)row_base * 512;
#pragma unroll
    for (int q = 0; q < 4; ++q) xcur[q] = xp[(size_t)(4 * q16 + q) * 512];
  }
  wg_barrier();

#pragma unroll 1
  for (int s = 0; s < 514; ++s) {
    // decoder y_{s-3} = h2_{s-3} @ lin_w + lin_b (MFMA on g0w0)
    if (yduty && s >= 3) {
      const int yb = (4 + ((s + 1) & 1)) * REG;
      f16x8 Yh[2];
      Yh[0] = *(const f16x8*)(ring + yb + ro0);
      Yh[1] = *(const f16x8*)(ring + yb + ro1);
      f32x4 ya = {lb, lb, lb, lb};
      ya = mmh(ya, Yh, Lw);
      if (c16 == 0) {
#pragma unroll
        for (int q = 0; q < 4; ++q)
          P.y[(size_t)(row_base + 4 * q16 + q) * 512 + (s - 3)] = ya[q];
      }
    }

    const int t = s - g;
    if (t >= 0 && t < 512) {
      // ---- A loads up front (single f16 plane)
      const int oR = (g * 2 + ((t + 1) & 1)) * REG;
      f16x8 Ah[2];
      Ah[0] = *(const f16x8*)(ring + oR + ro0);
      Ah[1] = *(const f16x8*)(ring + oR + ro1);
      f16x8 Xh[2];
      if (!din1) {
        const int oX = ((g - 1) * 2 + (t & 1)) * REG;
        Xh[0] = *(const f16x8*)(ring + oX + ro0);
        Xh[1] = *(const f16x8*)(ring + oX + ro1);
      }

      f32x4 aR  = {b_r, b_r, b_r, b_r};
      f32x4 aZ  = {b_z, b_z, b_z, b_z};
      f32x4 aHN = {b_hn, b_hn, b_hn, b_hn};
      f32x4 aIN = {b_in, b_in, b_in, b_in};
      aR  = mmh(aR,  Ah, Bh[0]);
      aZ  = mmh(aZ,  Ah, Bh[1]);
      aHN = mmh(aHN, Ah, Bh[2]);

      if (din1) {
#pragma unroll
        for (int q = 0; q < 4; ++q) {
          aR[q]  += xcur[q] * w_r;
          aZ[q]  += xcur[q] * w_z;
          aIN[q] += xcur[q] * w_n;
        }
        if (t + 1 < 512) {                      // prefetch next step's x
          const float* xp = P.xseq + (size_t)row_base * 512 + (t + 1);
#pragma unroll
          for (int q = 0; q < 4; ++q) xcur[q] = xp[(size_t)(4 * q16 + q) * 512];
        }
      } else {
        aR  = mmx(aR,  Xh, Bx[0]);
        aZ  = mmx(aZ,  Xh, Bx[1]);
        aIN = mmx(aIN, Xh, Bx[2]);
      }

      // ---- activations + state update (full fp32), publish to parity t&1
      unsigned short* wp = ring + (g * 2 + (t & 1)) * REG;
#pragma unroll
      for (int q = 0; q < 4; ++q) {
        float r = __builtin_amdgcn_rcpf(1.f + __expf(-aR[q]));
        float z = __builtin_amdgcn_rcpf(1.f + __expf(-aZ[q]));
        float na = aIN[q] + r * aHN[q];
        float e2 = __expf(2.f * na);
        float n  = __builtin_fmaf(-2.f, __builtin_amdgcn_rcpf(e2 + 1.f), 1.f);
        float h  = n + z * (hreg[q] - n);
        hreg[q]  = h;
        wp[wo[q]] = f2h(h);
      }

      // ---- encoder: store final hidden state (full fp32)
      if (!IS_DEC && t == 511) {
#pragma unroll
        for (int q = 0; q < 4; ++q)
          P.hfin_wr[((size_t)g * 2048 + row_base + 4 * q16 + q) * 64 + c] = hreg[q];
      }
    }
    wg_barrier();
  }

  // decoder epilogue: y_511 (h2_511 written at s=513 into region 5)
  if (yduty) {
    const int yb = 5 * REG;
    f16x8 Yh[2];
    Yh[0] = *(const f16x8*)(ring + yb + ro0);
    Yh[1] = *(const f16x8*)(ring + yb + ro1);
    f32x4 ya = {lb, lb, lb, lb};
    ya = mmh(ya, Yh, Lw);
    if (c16 == 0) {
#pragma unroll
      for (int q = 0; q < 4; ++q)
        P.y[(size_t)(row_base + 4 * q16 + q) * 512 + 511] = ya[q];
    }
  }
}

// ---------------------------------------------------------------------------
extern "C" void kernel_launch(void* const* d_in, const int* in_sizes, int n_in,
                              void* d_out, int out_size, void* d_ws, size_t ws_size,
                              hipStream_t stream) {
  (void)in_sizes; (void)n_in; (void)out_size; (void)ws_size;
  const float* inputs  = (const float*)d_in[0];
  const float* outputs = (const float*)d_in[1];

  unsigned short* frags = (unsigned short*)d_ws;            // 638976 B
  float* hfin = (float*)((char*)d_ws + 655360);             // 1.5 MB

  static const int ofs[6]  = {2, 6, 10, 14, 18, 22};  // enc0,enc1,enc2,c1,c2,c3
  static const int dins[6] = {1, 60, 60, 1, 60, 60};

  PrepArgs pa;
  for (int ci = 0; ci < 6; ++ci) {
    pa.w[ci * 2 + 0]   = (const float*)d_in[ofs[ci] + 0];  // wih
    pa.w[ci * 2 + 1]   = (const float*)d_in[ofs[ci] + 1];  // whh
    pa.din[ci * 2 + 0] = dins[ci];
    pa.din[ci * 2 + 1] = 60;
  }
  pa.w[12]   = (const float*)d_in[26];                     // lin_w
  pa.din[12] = 60;
  pa.out = frags;
  prep_frags<<<dim3(1248), dim3(256), 0, stream>>>(pa);

  PhaseArgs ea;
  ea.xseq = inputs; ea.frags = frags;
  for (int gg = 0; gg < 3; ++gg) {
    ea.cell[gg].bih     = (const float*)d_in[ofs[gg] + 2];
    ea.cell[gg].bhh     = (const float*)d_in[ofs[gg] + 3];
    ea.cell[gg].wih_vec = (const float*)d_in[ofs[gg] + 0];
  }
  ea.hfin_rd = hfin; ea.hfin_wr = hfin;
  ea.lin_b = (const float*)d_in[27];
  ea.y = (float*)d_out;
  gru_phase<0><<<dim3(128), dim3(768), 0, stream>>>(ea);

  PhaseArgs da = ea;
  da.xseq = outputs;
  for (int gg = 0; gg < 3; ++gg) {
    da.cell[gg].bih     = (const float*)d_in[ofs[3 + gg] + 2];
    da.cell[gg].bhh     = (const float*)d_in[ofs[3 + gg] + 3];
    da.cell[gg].wih_vec = (const float*)d_in[ofs[3 + gg] + 0];
  }
  gru_phase<1><<<dim3(128), dim3(768), 0, stream>>>(da);
}